// Round 6
// baseline (364.122 us; speedup 1.0000x reference)
//
#include <hip/hip_runtime.h>

#define NN 100000
#define EE 1600000
#define FDIM 224
#define OUTC 112
#define XBASE 32768
#define NPAD 100032

typedef __attribute__((ext_vector_type(8))) short bf16x8;
typedef __attribute__((ext_vector_type(8))) unsigned short u16x8;
typedef __attribute__((ext_vector_type(4))) float f32x4;
typedef __attribute__((ext_vector_type(2))) float f32x2;
typedef __attribute__((ext_vector_type(2))) unsigned short u16x2;

__device__ __forceinline__ unsigned short f2bf(float f) {
  unsigned u = __builtin_bit_cast(unsigned, f);
  u = (u + 0x7FFFu + ((u >> 16) & 1u)) >> 16;   // RNE
  return (unsigned short)u;
}
__device__ __forceinline__ float bf2f(unsigned short h) {
  return __builtin_bit_cast(float, (unsigned)h << 16);
}

// ---- prep kernels ------------------------------------------------------
__global__ void k_zero(unsigned int* p, int n) {
  int i = blockIdx.x * 256 + threadIdx.x;
  if (i < n) p[i] = 0u;
}

__global__ void k_scatter(const int* __restrict__ ei, unsigned char* __restrict__ act) {
  int e = blockIdx.x * 256 + threadIdx.x;
  if (e < EE) act[ei[e]] = 1;
}

// W1T: [512][128] bf16; W2T: [576][256] bf16 (rows 0..63 inv, 64..575 wemb)
__global__ void k_wprep(const float* __restrict__ invW1, const float* __restrict__ invW2,
                        const float* __restrict__ wembW1, const float* __restrict__ wembW2,
                        unsigned short* __restrict__ W1T, unsigned short* __restrict__ W2T) {
  int i = blockIdx.x * 256 + threadIdx.x;
  if (i < 512 * 128) {
    int n = i >> 7, k = i & 127;
    float v = (n < 256) ? invW1[k * 256 + n] : wembW1[k * 256 + (n - 256)];
    W1T[i] = f2bf(v);
  } else if (i < 512 * 128 + 576 * 256) {
    int t = i - 512 * 128;
    int n = t >> 8, k = t & 255;
    float v = (n < 64) ? invW2[k * 64 + n] : wembW2[k * 512 + (n - 64)];
    W2T[t] = f2bf(v);
  }
}

// ======================= SPLIT PATH =====================================
// k_A: H[NPAD][512] bf16 = silu(S @ W1cat / sqrt(128)). BM=64, 512 thr.
// H is stored LINEAR in global (LDS swizzle undone at writeback).
__global__ __launch_bounds__(512, 2) void k_A(
    const float* __restrict__ feats,
    const unsigned short* __restrict__ W1T,
    unsigned short* __restrict__ H) {
  __shared__ char smem[65536];
  const int tid = threadIdx.x;
  const int lane = tid & 63;
  const int wv = tid >> 6;
  const int wm = wv & 1;         // row half (32 rows)
  const int wn = wv >> 1;        // col slice (128 cols)
  const int o = lane & 15;
  const int g = lane >> 4;
  const int base = blockIdx.x * 64;
  const float rs128 = 0.08838834764831845f;

  f32x4 acc[2][8];
#pragma unroll
  for (int mt = 0; mt < 2; ++mt)
#pragma unroll
    for (int nt = 0; nt < 8; ++nt)
      acc[mt][nt] = (f32x4){0.f, 0.f, 0.f, 0.f};

  const float* arow[2];
#pragma unroll
  for (int mt = 0; mt < 2; ++mt) {
    int r = base + wm * 32 + mt * 16 + o;
    if (r > NN - 1) r = NN - 1;
    arow[mt] = feats + (size_t)r * FDIM;
  }

#pragma unroll 2
  for (int ks = 0; ks < 4; ++ks) {
    bf16x8 af[2];
#pragma unroll
    for (int mt = 0; mt < 2; ++mt) {
      const float* p = arow[mt] + ks * 32 + g * 8;
      f32x4 x0 = *(const f32x4*)p;
      f32x4 x1 = *(const f32x4*)(p + 4);
      bf16x8 a;
      a[0] = (short)f2bf(x0[0]); a[1] = (short)f2bf(x0[1]);
      a[2] = (short)f2bf(x0[2]); a[3] = (short)f2bf(x0[3]);
      a[4] = (short)f2bf(x1[0]); a[5] = (short)f2bf(x1[1]);
      a[6] = (short)f2bf(x1[2]); a[7] = (short)f2bf(x1[3]);
      af[mt] = a;
    }
#pragma unroll
    for (int nt = 0; nt < 8; ++nt) {
      bf16x8 b = *(const bf16x8*)(W1T + (wn * 128 + nt * 16 + o) * 128 + ks * 32 + g * 8);
#pragma unroll
      for (int mt = 0; mt < 2; ++mt)
        acc[mt][nt] = __builtin_amdgcn_mfma_f32_16x16x32_bf16(af[mt], b, acc[mt][nt], 0, 0, 0);
    }
  }

  // silu -> LDS (swizzled)
#pragma unroll
  for (int mt = 0; mt < 2; ++mt)
#pragma unroll
    for (int nt = 0; nt < 8; ++nt)
#pragma unroll
      for (int r4 = 0; r4 < 4; ++r4) {
        int row = wm * 32 + mt * 16 + g * 4 + r4;
        int col = wn * 128 + nt * 16 + o;
        float v = acc[mt][nt][r4] * rs128;
        float h = v / (1.f + __expf(-v));
        int byte = (row * 1024 + col * 2) ^ ((row & 15) << 4);
        *(unsigned short*)(smem + byte) = f2bf(h);
      }
  __syncthreads();

  // coalesced H writeback: LDS read swizzled, global write LINEAR
#pragma unroll
  for (int it = 0; it < 8; ++it) {
    int row = wv * 8 + it;
    int pb = (lane * 16) ^ ((row & 15) << 4);
    f32x4 v = *(const f32x4*)(smem + row * 1024 + pb);
    *(f32x4*)((char*)H + (size_t)(base + row) * 1024 + lane * 16) = v;
  }
}

// k_B: wemb GEMM -> Wm[NPAD][512] bf16 (scaled 1/16, LINEAR layout),
//      inv GEMM -> out cols 0..63
__global__ __launch_bounds__(512, 2) void k_B(
    const unsigned short* __restrict__ H,
    const unsigned short* __restrict__ W2T,
    const unsigned char* __restrict__ act,
    unsigned short* __restrict__ Wm,
    float* __restrict__ out) {
  __shared__ char smem[65536];
  const int tid = threadIdx.x;
  const int lane = tid & 63;
  const int wv = tid >> 6;
  const int wm = wv & 1;
  const int wn = wv >> 1;
  const int o = lane & 15;
  const int g = lane >> 4;
  const int base = blockIdx.x * 64;
  const float inv16 = 0.0625f;

  f32x4 acc[2][8];
  f32x4 acc2[2];
#pragma unroll
  for (int mt = 0; mt < 2; ++mt) {
    acc2[mt] = (f32x4){0.f, 0.f, 0.f, 0.f};
#pragma unroll
    for (int nt = 0; nt < 8; ++nt)
      acc[mt][nt] = (f32x4){0.f, 0.f, 0.f, 0.f};
  }

  const unsigned short* hrow[2];
#pragma unroll
  for (int mt = 0; mt < 2; ++mt)
    hrow[mt] = H + (size_t)(base + wm * 32 + mt * 16 + o) * 512;

#pragma unroll 2
  for (int ks = 0; ks < 8; ++ks) {
    bf16x8 ai[2], aw[2];
#pragma unroll
    for (int mt = 0; mt < 2; ++mt) {
      ai[mt] = *(const bf16x8*)(hrow[mt] + ks * 32 + g * 8);
      aw[mt] = *(const bf16x8*)(hrow[mt] + 256 + ks * 32 + g * 8);
    }
    bf16x8 b2 = *(const bf16x8*)(W2T + (wn * 16 + o) * 256 + ks * 32 + g * 8);
#pragma unroll
    for (int mt = 0; mt < 2; ++mt)
      acc2[mt] = __builtin_amdgcn_mfma_f32_16x16x32_bf16(ai[mt], b2, acc2[mt], 0, 0, 0);
#pragma unroll
    for (int nt = 0; nt < 8; ++nt) {
      bf16x8 b1 = *(const bf16x8*)(W2T + 16384 + (wn * 128 + nt * 16 + o) * 256 + ks * 32 + g * 8);
#pragma unroll
      for (int mt = 0; mt < 2; ++mt)
        acc[mt][nt] = __builtin_amdgcn_mfma_f32_16x16x32_bf16(aw[mt], b1, acc[mt][nt], 0, 0, 0);
    }
  }

  // inv output (cols 0..63), masked
#pragma unroll
  for (int mt = 0; mt < 2; ++mt)
#pragma unroll
    for (int r4 = 0; r4 < 4; ++r4) {
      int node = base + wm * 32 + mt * 16 + g * 4 + r4;
      if (node < NN) {
        float s = act[node] ? inv16 : 0.f;
        __builtin_nontemporal_store(acc2[mt][r4] * s, out + (size_t)node * OUTC + wn * 16 + o);
      }
    }

  // wemb -> LDS (scaled), swizzled
#pragma unroll
  for (int mt = 0; mt < 2; ++mt)
#pragma unroll
    for (int nt = 0; nt < 8; ++nt)
#pragma unroll
      for (int r4 = 0; r4 < 4; ++r4) {
        int row = wm * 32 + mt * 16 + g * 4 + r4;
        int col = wn * 128 + nt * 16 + o;
        int byte = (row * 1024 + col * 2) ^ ((row & 15) << 4);
        *(unsigned short*)(smem + byte) = f2bf(acc[mt][nt][r4] * inv16);
      }
  __syncthreads();

  // coalesced Wm writeback: LDS read swizzled, global write LINEAR
#pragma unroll
  for (int it = 0; it < 8; ++it) {
    int row = wv * 8 + it;
    int pb = (lane * 16) ^ ((row & 15) << 4);
    f32x4 v = *(const f32x4*)(smem + row * 1024 + pb);
    *(f32x4*)((char*)Wm + (size_t)(base + row) * 1024 + lane * 16) = v;
  }
}

// k_C: eq[n,o,m] = (1/sqrt(32)) * sum_i x[n,i,m] * Wm[n][i*16+o], masked.
// 16 nodes/block, 16 thr/node (thread q owns channel q). 6250*16 = NN exact.
__global__ __launch_bounds__(256, 4) void k_C(
    const float* __restrict__ feats,
    const unsigned short* __restrict__ Wm,
    const unsigned char* __restrict__ act,
    float* __restrict__ out) {
  const int tid = threadIdx.x;
  const int nloc = tid >> 4;
  const int q = tid & 15;
  const int node = blockIdx.x * 16 + nloc;
  const float rs32 = 0.17677669529663687f;

  const float* xp = feats + (size_t)node * FDIM + 128;
  const unsigned short* wp = Wm + (size_t)node * 512 + q;

  float eq0 = 0.f, eq1 = 0.f, eq2 = 0.f;

#pragma unroll 2
  for (int c = 0; c < 4; ++c) {          // 8 i-values per chunk (24 floats of x)
    f32x4 xv[6];
#pragma unroll
    for (int j = 0; j < 6; ++j) xv[j] = *(const f32x4*)(xp + c * 24 + j * 4);
    unsigned short w8[8];
#pragma unroll
    for (int di = 0; di < 8; ++di) w8[di] = wp[(c * 8 + di) * 16];
#pragma unroll
    for (int di = 0; di < 8; ++di) {
      float wf = bf2f(w8[di]);
      eq0 += xv[(di * 3 + 0) >> 2][(di * 3 + 0) & 3] * wf;
      eq1 += xv[(di * 3 + 1) >> 2][(di * 3 + 1) & 3] * wf;
      eq2 += xv[(di * 3 + 2) >> 2][(di * 3 + 2) & 3] * wf;
    }
  }

  float s = act[node] ? rs32 : 0.f;
  float* op = out + (size_t)node * OUTC + 64 + q * 3;
  __builtin_nontemporal_store(eq0 * s, op + 0);
  __builtin_nontemporal_store(eq1 * s, op + 1);
  __builtin_nontemporal_store(eq2 * s, op + 2);
}

// ======================= FALLBACK MONOLITH (r4) =========================
__global__ __launch_bounds__(512, 4) void k_main(
    const float* __restrict__ feats,
    const unsigned short* __restrict__ W1T,
    const unsigned short* __restrict__ W2T,
    const unsigned char* __restrict__ act,
    float* __restrict__ out) {
  __shared__ char smem[38912];
  const int tid = threadIdx.x;
  const int lane = tid & 63;
  const int wv = tid >> 6;
  const int o = lane & 15;
  const int g = lane >> 4;
  const int base = blockIdx.x * 32;

  const float rs128 = 0.08838834764831845f;
  const float inv16 = 0.0625f;
  const float rs32  = 0.17677669529663687f;

  const int xn = tid >> 4;
  const int xs = tid & 15;
  const float* xsrc = feats + (size_t)(base + xn) * FDIM + 128 + xs * 6;
  f32x2 xa = *(const f32x2*)(xsrc);
  f32x2 xb = *(const f32x2*)(xsrc + 2);
  f32x2 xc = *(const f32x2*)(xsrc + 4);

  f32x4 acc[2][4];
#pragma unroll
  for (int mt = 0; mt < 2; ++mt)
#pragma unroll
    for (int nt = 0; nt < 4; ++nt)
      acc[mt][nt] = (f32x4){0.f, 0.f, 0.f, 0.f};

  const float* arow0 = feats + (size_t)(base + o) * FDIM;
  const float* arow1 = arow0 + 16 * FDIM;

#pragma unroll 2
  for (int ks = 0; ks < 4; ++ks) {
    bf16x8 af[2];
#pragma unroll
    for (int mt = 0; mt < 2; ++mt) {
      const float* p = (mt ? arow1 : arow0) + ks * 32 + g * 8;
      f32x4 x0 = *(const f32x4*)p;
      f32x4 x1 = *(const f32x4*)(p + 4);
      bf16x8 a;
      a[0] = (short)f2bf(x0[0]); a[1] = (short)f2bf(x0[1]);
      a[2] = (short)f2bf(x0[2]); a[3] = (short)f2bf(x0[3]);
      a[4] = (short)f2bf(x1[0]); a[5] = (short)f2bf(x1[1]);
      a[6] = (short)f2bf(x1[2]); a[7] = (short)f2bf(x1[3]);
      af[mt] = a;
    }
#pragma unroll
    for (int nt = 0; nt < 4; ++nt) {
      int n = wv * 64 + nt * 16 + o;
      bf16x8 b = *(const bf16x8*)(W1T + n * 128 + ks * 32 + g * 8);
#pragma unroll
      for (int mt = 0; mt < 2; ++mt)
        acc[mt][nt] = __builtin_amdgcn_mfma_f32_16x16x32_bf16(af[mt], b, acc[mt][nt], 0, 0, 0);
    }
  }

#pragma unroll
  for (int mt = 0; mt < 2; ++mt)
#pragma unroll
    for (int nt = 0; nt < 4; ++nt)
#pragma unroll
      for (int r4 = 0; r4 < 4; ++r4) {
        int row = mt * 16 + g * 4 + r4;
        int col = wv * 64 + nt * 16 + o;
        float v = acc[mt][nt][r4] * rs128;
        float h = v / (1.f + __expf(-v));
        int byte = (row * 1024 + col * 2) ^ ((row & 15) << 4);
        *(unsigned short*)(smem + byte) = f2bf(h);
      }
  {
    int xb0 = XBASE + xn * 64 + xs * 4;
    *(u16x2*)(smem + xb0)        = (u16x2){f2bf(xa[0]), f2bf(xb[1])};
    *(u16x2*)(smem + xb0 + 2048) = (u16x2){f2bf(xa[1]), f2bf(xc[0])};
    *(u16x2*)(smem + xb0 + 4096) = (u16x2){f2bf(xb[0]), f2bf(xc[1])};
  }
  __syncthreads();

  const int mtw = wv & 1;
  const int ct = wv >> 1;
  f32x4 acc2 = (f32x4){0.f, 0.f, 0.f, 0.f};
#pragma unroll
  for (int mt = 0; mt < 2; ++mt)
#pragma unroll
    for (int nt = 0; nt < 4; ++nt)
      acc[mt][nt] = (f32x4){0.f, 0.f, 0.f, 0.f};

#pragma unroll 2
  for (int ks = 0; ks < 8; ++ks) {
    int rlo = mtw * 16 + o;
    bf16x8 aflo = *(const bf16x8*)(smem + ((rlo * 1024 + ks * 64 + g * 16) ^ ((rlo & 15) << 4)));
    bf16x8 afhi[2];
#pragma unroll
    for (int mt = 0; mt < 2; ++mt) {
      int row = mt * 16 + o;
      afhi[mt] = *(const bf16x8*)(smem + ((row * 1024 + 512 + ks * 64 + g * 16) ^ ((row & 15) << 4)));
    }
    bf16x8 b2 = *(const bf16x8*)(W2T + (ct * 16 + o) * 256 + ks * 32 + g * 8);
    acc2 = __builtin_amdgcn_mfma_f32_16x16x32_bf16(aflo, b2, acc2, 0, 0, 0);
#pragma unroll
    for (int nt = 0; nt < 4; ++nt) {
      int wc = wv * 64 + nt * 16 + o;
      bf16x8 b1 = *(const bf16x8*)(W2T + 16384 + wc * 256 + ks * 32 + g * 8);
#pragma unroll
      for (int mt = 0; mt < 2; ++mt)
        acc[mt][nt] = __builtin_amdgcn_mfma_f32_16x16x32_bf16(afhi[mt], b1, acc[mt][nt], 0, 0, 0);
    }
  }

#pragma unroll
  for (int r4 = 0; r4 < 4; ++r4) {
    int node = base + mtw * 16 + g * 4 + r4;
    float s = act[node] ? inv16 : 0.f;
    __builtin_nontemporal_store(acc2[r4] * s, out + (size_t)node * OUTC + ct * 16 + o);
  }
  __syncthreads();

#pragma unroll
  for (int mt = 0; mt < 2; ++mt)
#pragma unroll
    for (int nt = 0; nt < 4; ++nt)
#pragma unroll
      for (int r4 = 0; r4 < 4; ++r4) {
        int row = mt * 16 + g * 4 + r4;
        int col = wv * 64 + nt * 16 + o;
        int byte = (row * 1024 + col * 2) ^ ((row & 15) << 4);
        *(unsigned short*)(smem + byte) = f2bf(acc[mt][nt][r4] * inv16);
      }
  __syncthreads();

  const int nloc = tid >> 4;
  const int q = tid & 15;
  const int node = base + nloc;

  float wreg[32];
#pragma unroll
  for (int i = 0; i < 32; ++i) {
    int byte = (nloc * 1024 + (i * 16 + q) * 2) ^ ((nloc & 15) << 4);
    wreg[i] = bf2f(*(const unsigned short*)(smem + byte));
  }

  float eq[3] = {0.f, 0.f, 0.f};
#pragma unroll
  for (int m = 0; m < 3; ++m) {
#pragma unroll
    for (int rb = 0; rb < 4; ++rb) {
      u16x8 ch = *(const u16x8*)(smem + XBASE + m * 2048 + nloc * 64 + rb * 16);
#pragma unroll
      for (int di = 0; di < 8; ++di)
        eq[m] += bf2f(ch[di]) * wreg[rb * 8 + di];
    }
  }

  float s = act[node] ? rs32 : 0.f;
  float* op = out + (size_t)node * OUTC + 64 + q * 3;
  __builtin_nontemporal_store(eq[0] * s, op + 0);
  __builtin_nontemporal_store(eq[1] * s, op + 1);
  __builtin_nontemporal_store(eq[2] * s, op + 2);
}

// ---- launch ------------------------------------------------------------
extern "C" void kernel_launch(void* const* d_in, const int* in_sizes, int n_in,
                              void* d_out, int out_size, void* d_ws, size_t ws_size,
                              hipStream_t stream) {
  const float* feats = (const float*)d_in[0];
  const int* ei = (const int*)d_in[1];
  const float* invW1 = (const float*)d_in[2];
  const float* invW2 = (const float*)d_in[3];
  const float* wembW1 = (const float*)d_in[4];
  const float* wembW2 = (const float*)d_in[5];
  float* out = (float*)d_out;

  char* ws = (char*)d_ws;
  unsigned short* W1T = (unsigned short*)ws;                      // 131072 B
  unsigned short* W2T = (unsigned short*)(ws + 131072);           // 294912 B
  unsigned char* act = (unsigned char*)(ws + 131072 + 294912);    // 100096 B
  const size_t hoff = 131072 + 294912 + 100096;                   // 526080
  const size_t hbytes = (size_t)NPAD * 512 * 2;                   // 102432768
  unsigned short* H  = (unsigned short*)(ws + hoff);
  unsigned short* Wm = (unsigned short*)(ws + hoff + hbytes);
  const size_t need = hoff + 2 * hbytes;                          // 205391616

  k_zero<<<98, 256, 0, stream>>>((unsigned int*)act, 25000);
  k_scatter<<<6250, 256, 0, stream>>>(ei, act);
  k_wprep<<<832, 256, 0, stream>>>(invW1, invW2, wembW1, wembW2, W1T, W2T);

  if (ws_size >= need) {
    k_A<<<1563, 512, 0, stream>>>(feats, W1T, H);
    k_B<<<1563, 512, 0, stream>>>(H, W2T, act, Wm, out);
    k_C<<<6250, 256, 0, stream>>>(feats, Wm, act, out);
  } else {
    k_main<<<3125, 512, 0, stream>>>(feats, W1T, W2T, act, out);
  }
}

// Round 7
// 247.529 us; speedup vs baseline: 1.4710x; 1.4710x over previous
//
#include <hip/hip_runtime.h>

#define NN 100000
#define EE 1600000
#define FDIM 224
#define OUTC 112
#define XBASE 32768

typedef __attribute__((ext_vector_type(8))) short bf16x8;
typedef __attribute__((ext_vector_type(8))) unsigned short u16x8;
typedef __attribute__((ext_vector_type(4))) float f32x4;
typedef __attribute__((ext_vector_type(2))) float f32x2;
typedef __attribute__((ext_vector_type(2))) unsigned short u16x2;

__device__ __forceinline__ unsigned short f2bf(float f) {
  unsigned u = __builtin_bit_cast(unsigned, f);
  u = (u + 0x7FFFu + ((u >> 16) & 1u)) >> 16;   // RNE
  return (unsigned short)u;
}
__device__ __forceinline__ float bf2f(unsigned short h) {
  return __builtin_bit_cast(float, (unsigned)h << 16);
}
__device__ __forceinline__ bf16x8 cvt8(f32x4 x0, f32x4 x1) {
  bf16x8 a;
  a[0] = (short)f2bf(x0[0]); a[1] = (short)f2bf(x0[1]);
  a[2] = (short)f2bf(x0[2]); a[3] = (short)f2bf(x0[3]);
  a[4] = (short)f2bf(x1[0]); a[5] = (short)f2bf(x1[1]);
  a[6] = (short)f2bf(x1[2]); a[7] = (short)f2bf(x1[3]);
  return a;
}

// ---- prep kernels ------------------------------------------------------
__global__ void k_zero(unsigned int* p, int n) {
  int i = blockIdx.x * 256 + threadIdx.x;
  if (i < n) p[i] = 0u;
}

// test-and-set: avoids cross-XCD dirty-line thrash (act is ~all-ones)
__global__ void k_scatter(const int* __restrict__ ei, unsigned char* __restrict__ act) {
  int e = blockIdx.x * 256 + threadIdx.x;
  if (e < EE) {
    int n = ei[e];
    if (!act[n]) act[n] = 1;
  }
}

// W1T: [512][128] bf16; W2T: [576][256] bf16 (rows 0..63 inv, 64..575 wemb)
__global__ void k_wprep(const float* __restrict__ invW1, const float* __restrict__ invW2,
                        const float* __restrict__ wembW1, const float* __restrict__ wembW2,
                        unsigned short* __restrict__ W1T, unsigned short* __restrict__ W2T) {
  int i = blockIdx.x * 256 + threadIdx.x;
  if (i < 512 * 128) {
    int n = i >> 7, k = i & 127;
    float v = (n < 256) ? invW1[k * 256 + n] : wembW1[k * 256 + (n - 256)];
    W1T[i] = f2bf(v);
  } else if (i < 512 * 128 + 576 * 256) {
    int t = i - 512 * 128;
    int n = t >> 8, k = t & 255;
    float v = (n < 64) ? invW2[k * 64 + n] : wembW2[k * 512 + (n - 64)];
    W2T[t] = f2bf(v);
  }
}

// ---- fused main kernel (r4 structure + hand software-pipeline) --------
// 32 nodes / block, 512 threads (8 waves). LDS 38KB. Grid 3125 exact.
__global__ __launch_bounds__(512, 4) void k_main(
    const float* __restrict__ feats,
    const unsigned short* __restrict__ W1T,
    const unsigned short* __restrict__ W2T,
    const unsigned char* __restrict__ act,
    float* __restrict__ out) {
  __shared__ char smem[38912];
  const int tid = threadIdx.x;
  const int lane = tid & 63;
  const int wv = tid >> 6;
  const int o = lane & 15;
  const int g = lane >> 4;
  const int base = blockIdx.x * 32;

  const float rs128 = 0.08838834764831845f;
  const float inv16 = 0.0625f;
  const float rs32  = 0.17677669529663687f;

  // x prefetch (consumed in phase C via LDS)
  const int xn = tid >> 4;
  const int xs = tid & 15;
  const float* xsrc = feats + (size_t)(base + xn) * FDIM + 128 + xs * 6;
  f32x2 xa = *(const f32x2*)(xsrc);
  f32x2 xb = *(const f32x2*)(xsrc + 2);
  f32x2 xc = *(const f32x2*)(xsrc + 4);

  // ================= Phase A: H = silu(S @ W1cat / sqrt(128)) ==========
  f32x4 acc[2][4];
#pragma unroll
  for (int mt = 0; mt < 2; ++mt)
#pragma unroll
    for (int nt = 0; nt < 4; ++nt)
      acc[mt][nt] = (f32x4){0.f, 0.f, 0.f, 0.f};

  const float* arow0 = feats + (size_t)(base + o) * FDIM + g * 8;
  const float* arow1 = arow0 + 16 * FDIM;
  const unsigned short* w1p = W1T + (wv * 64 + o) * 128 + g * 8;

#define LOADS(KS, D) do { \
    const float* p0_ = arow0 + (KS) * 32; \
    const float* p1_ = arow1 + (KS) * 32; \
    D[0] = *(const f32x4*)p0_; D[1] = *(const f32x4*)(p0_ + 4); \
    D[2] = *(const f32x4*)p1_; D[3] = *(const f32x4*)(p1_ + 4); \
  } while (0)
#define LOADW1(KS, D) do { \
    _Pragma("unroll") \
    for (int nt_ = 0; nt_ < 4; ++nt_) \
      D[nt_] = *(const bf16x8*)(w1p + nt_ * 2048 + (KS) * 32); \
  } while (0)
#define COMPA(S, W) do { \
    bf16x8 af0_ = cvt8(S[0], S[1]); \
    bf16x8 af1_ = cvt8(S[2], S[3]); \
    _Pragma("unroll") \
    for (int nt_ = 0; nt_ < 4; ++nt_) { \
      acc[0][nt_] = __builtin_amdgcn_mfma_f32_16x16x32_bf16(af0_, W[nt_], acc[0][nt_], 0, 0, 0); \
      acc[1][nt_] = __builtin_amdgcn_mfma_f32_16x16x32_bf16(af1_, W[nt_], acc[1][nt_], 0, 0, 0); \
    } \
  } while (0)

  {
    f32x4 s0[4], s1[4];
    bf16x8 w0[4], w1f[4];
    LOADS(0, s0); LOADW1(0, w0);
#pragma unroll 1
    for (int ks = 0; ks < 4; ks += 2) {
      LOADS(ks + 1, s1); LOADW1(ks + 1, w1f);
      COMPA(s0, w0);
      int k2 = (ks + 2) & 3;
      LOADS(k2, s0); LOADW1(k2, w0);
      COMPA(s1, w1f);
    }
  }

  // silu + bf16 -> LDS (swizzled)
#pragma unroll
  for (int mt = 0; mt < 2; ++mt)
#pragma unroll
    for (int nt = 0; nt < 4; ++nt)
#pragma unroll
      for (int r4 = 0; r4 < 4; ++r4) {
        int row = mt * 16 + g * 4 + r4;
        int col = wv * 64 + nt * 16 + o;
        float v = acc[mt][nt][r4] * rs128;
        float h = v / (1.f + __expf(-v));
        int byte = (row * 1024 + col * 2) ^ ((row & 15) << 4);
        *(unsigned short*)(smem + byte) = f2bf(h);
      }
  // x -> LDS planes
  {
    int xb0 = XBASE + xn * 64 + xs * 4;
    *(u16x2*)(smem + xb0)        = (u16x2){f2bf(xa[0]), f2bf(xb[1])};
    *(u16x2*)(smem + xb0 + 2048) = (u16x2){f2bf(xa[1]), f2bf(xc[0])};
    *(u16x2*)(smem + xb0 + 4096) = (u16x2){f2bf(xb[0]), f2bf(xc[1])};
  }
  __syncthreads();

  // ====== Phase B (merged inv+wemb), software-pipelined over ks =========
  const int mtw = wv & 1;
  const int ct = wv >> 1;
  f32x4 acc2 = (f32x4){0.f, 0.f, 0.f, 0.f};
#pragma unroll
  for (int mt = 0; mt < 2; ++mt)
#pragma unroll
    for (int nt = 0; nt < 4; ++nt)
      acc[mt][nt] = (f32x4){0.f, 0.f, 0.f, 0.f};

  const unsigned short* w2i = W2T + (ct * 16 + o) * 256 + g * 8;
  const unsigned short* w2w = W2T + 16384 + (wv * 64 + o) * 256 + g * 8;

#define LOADB(KS, I, V) do { \
    I = *(const bf16x8*)(w2i + (KS) * 32); \
    _Pragma("unroll") \
    for (int nt_ = 0; nt_ < 4; ++nt_) \
      V[nt_] = *(const bf16x8*)(w2w + nt_ * 4096 + (KS) * 32); \
  } while (0)
#define COMPB(KS, I, V) do { \
    int rlo_ = mtw * 16 + o; \
    bf16x8 aflo_ = *(const bf16x8*)(smem + ((rlo_ * 1024 + (KS) * 64 + g * 16) ^ ((rlo_ & 15) << 4))); \
    bf16x8 afh0_ = *(const bf16x8*)(smem + ((o * 1024 + 512 + (KS) * 64 + g * 16) ^ ((o & 15) << 4))); \
    bf16x8 afh1_ = *(const bf16x8*)(smem + (((16 + o) * 1024 + 512 + (KS) * 64 + g * 16) ^ (((16 + o) & 15) << 4))); \
    acc2 = __builtin_amdgcn_mfma_f32_16x16x32_bf16(aflo_, I, acc2, 0, 0, 0); \
    _Pragma("unroll") \
    for (int nt_ = 0; nt_ < 4; ++nt_) { \
      acc[0][nt_] = __builtin_amdgcn_mfma_f32_16x16x32_bf16(afh0_, V[nt_], acc[0][nt_], 0, 0, 0); \
      acc[1][nt_] = __builtin_amdgcn_mfma_f32_16x16x32_bf16(afh1_, V[nt_], acc[1][nt_], 0, 0, 0); \
    } \
  } while (0)

  {
    bf16x8 i0, i1, v0[4], v1[4];
    LOADB(0, i0, v0);
#pragma unroll 1
    for (int ks = 0; ks < 8; ks += 2) {
      LOADB(ks + 1, i1, v1);
      COMPB(ks, i0, v0);
      LOADB((ks + 2) & 7, i0, v0);
      COMPB(ks + 1, i1, v1);
    }
  }

  // inv output (cols 0..63), masked
#pragma unroll
  for (int r4 = 0; r4 < 4; ++r4) {
    int node = base + mtw * 16 + g * 4 + r4;
    float s = act[node] ? inv16 : 0.f;
    __builtin_nontemporal_store(acc2[r4] * s, out + (size_t)node * OUTC + ct * 16 + o);
  }
  __syncthreads();   // all H reads done -> LDS reusable

  // wemb accs -> LDS as bf16 (scaled by 1/16), same swizzle
#pragma unroll
  for (int mt = 0; mt < 2; ++mt)
#pragma unroll
    for (int nt = 0; nt < 4; ++nt)
#pragma unroll
      for (int r4 = 0; r4 < 4; ++r4) {
        int row = mt * 16 + g * 4 + r4;
        int col = wv * 64 + nt * 16 + o;
        int byte = (row * 1024 + col * 2) ^ ((row & 15) << 4);
        *(unsigned short*)(smem + byte) = f2bf(acc[mt][nt][r4] * inv16);
      }
  __syncthreads();

  // ================= Phase C: eq[n,o,m] = sum_i x[m][n][i]*w[n][i,o] ====
  const int nloc = tid >> 4;
  const int q = tid & 15;
  const int node = base + nloc;

  float wreg[32];
#pragma unroll
  for (int i = 0; i < 32; ++i) {
    int byte = (nloc * 1024 + (i * 16 + q) * 2) ^ ((nloc & 15) << 4);
    wreg[i] = bf2f(*(const unsigned short*)(smem + byte));
  }

  float eq[3] = {0.f, 0.f, 0.f};
#pragma unroll
  for (int m = 0; m < 3; ++m) {
#pragma unroll
    for (int rb = 0; rb < 4; ++rb) {
      u16x8 ch = *(const u16x8*)(smem + XBASE + m * 2048 + nloc * 64 + rb * 16);
#pragma unroll
      for (int di = 0; di < 8; ++di)
        eq[m] += bf2f(ch[di]) * wreg[rb * 8 + di];
    }
  }

  float s = act[node] ? rs32 : 0.f;
  float* op = out + (size_t)node * OUTC + 64 + q * 3;
  __builtin_nontemporal_store(eq[0] * s, op + 0);
  __builtin_nontemporal_store(eq[1] * s, op + 1);
  __builtin_nontemporal_store(eq[2] * s, op + 2);
}

// ---- launch ------------------------------------------------------------
extern "C" void kernel_launch(void* const* d_in, const int* in_sizes, int n_in,
                              void* d_out, int out_size, void* d_ws, size_t ws_size,
                              hipStream_t stream) {
  const float* feats = (const float*)d_in[0];
  const int* ei = (const int*)d_in[1];
  const float* invW1 = (const float*)d_in[2];
  const float* invW2 = (const float*)d_in[3];
  const float* wembW1 = (const float*)d_in[4];
  const float* wembW2 = (const float*)d_in[5];
  float* out = (float*)d_out;

  char* ws = (char*)d_ws;
  unsigned short* W1T = (unsigned short*)ws;                      // 131072 B
  unsigned short* W2T = (unsigned short*)(ws + 131072);           // 294912 B
  unsigned char* act = (unsigned char*)(ws + 131072 + 294912);    // 100096 B

  k_zero<<<98, 256, 0, stream>>>((unsigned int*)act, 25000);
  k_scatter<<<6250, 256, 0, stream>>>(ei, act);
  k_wprep<<<832, 256, 0, stream>>>(invW1, invW2, wembW1, wembW2, W1T, W2T);
  k_main<<<3125, 512, 0, stream>>>(feats, W1T, W2T, act, out);
}

// Round 8
// 231.835 us; speedup vs baseline: 1.5706x; 1.0677x over previous
//
#include <hip/hip_runtime.h>

#define NN 100000
#define EE 1600000
#define FDIM 224
#define OUTC 112
#define NPAD 100032           // 1563 * 64

// LDS layout (bytes)
#define STG 0                 // stage scalars [64][128] bf16 (16KB); reused as Wm bufA
#define HB  16384             // Hbuf [64][256] bf16 (32KB)
#define WMB 49152             // Wm bufB (16KB)

typedef __attribute__((ext_vector_type(8))) short bf16x8;
typedef __attribute__((ext_vector_type(8))) unsigned short u16x8;
typedef __attribute__((ext_vector_type(2))) unsigned short u16x2;
typedef __attribute__((ext_vector_type(4))) float f32x4;
typedef __attribute__((ext_vector_type(2))) float f32x2;

__device__ __forceinline__ unsigned short f2bf(float f) {
  unsigned u = __builtin_bit_cast(unsigned, f);
  u = (u + 0x7FFFu + ((u >> 16) & 1u)) >> 16;   // RNE
  return (unsigned short)u;
}
__device__ __forceinline__ float bf2f(unsigned short h) {
  return __builtin_bit_cast(float, (unsigned)h << 16);
}

// ---- prep kernels ------------------------------------------------------
__global__ void k_zero(unsigned int* p, int n) {
  int i = blockIdx.x * 256 + threadIdx.x;
  if (i < n) p[i] = 0u;
}

__global__ void k_scatter(const int* __restrict__ ei, unsigned char* __restrict__ act) {
  int e = blockIdx.x * 256 + threadIdx.x;
  if (e < EE) {
    int n = ei[e];
    if (!act[n]) act[n] = 1;
  }
}

// W1T: [512][128] bf16 ; W2T: [576][256] bf16 (rows 0..63 inv, 64..575 wemb)
__global__ void k_wprep(const float* __restrict__ invW1, const float* __restrict__ invW2,
                        const float* __restrict__ wembW1, const float* __restrict__ wembW2,
                        unsigned short* __restrict__ W1T, unsigned short* __restrict__ W2T) {
  int i = blockIdx.x * 256 + threadIdx.x;
  if (i < 512 * 128) {
    int n = i >> 7, k = i & 127;
    float v = (n < 256) ? invW1[k * 256 + n] : wembW1[k * 256 + (n - 256)];
    W1T[i] = f2bf(v);
  } else if (i < 512 * 128 + 576 * 256) {
    int t = i - 512 * 128;
    int n = t >> 8, k = t & 255;
    float v = (n < 64) ? invW2[k * 64 + n] : wembW2[k * 512 + (n - 64)];
    W2T[t] = f2bf(v);
  }
}

// feats f32 -> featsBF bf16 [NPAD][224], tail rows zeroed
__global__ void k_fprep(const float* __restrict__ feats, unsigned short* __restrict__ fb) {
  const int TOT = NPAD * 28;     // u16x8 tasks
  for (int e = blockIdx.x * 256 + threadIdx.x; e < TOT; e += gridDim.x * 256) {
    int row = e / 28, c8 = e % 28;
    u16x8 v;
    if (row < NN) {
      const float* p = feats + (size_t)row * FDIM + c8 * 8;
      f32x4 a = *(const f32x4*)p;
      f32x4 b = *(const f32x4*)(p + 4);
      v[0] = f2bf(a[0]); v[1] = f2bf(a[1]); v[2] = f2bf(a[2]); v[3] = f2bf(a[3]);
      v[4] = f2bf(b[0]); v[5] = f2bf(b[1]); v[6] = f2bf(b[2]); v[7] = f2bf(b[3]);
    } else {
      v = (u16x8){0, 0, 0, 0, 0, 0, 0, 0};
    }
    *(u16x8*)(fb + (size_t)row * FDIM + c8 * 8) = v;
  }
}

// ---- fused main kernel -------------------------------------------------
// 64 nodes/block, 512 thr (8 waves), LDS 64KB -> 2 blocks/CU.
__global__ __launch_bounds__(512, 4) void k_main(
    const unsigned short* __restrict__ fB,
    const unsigned short* __restrict__ W1T,
    const unsigned short* __restrict__ W2T,
    const unsigned char* __restrict__ act,
    float* __restrict__ out) {
  __shared__ char smem[65536];
  const int tid = threadIdx.x;
  const int lane = tid & 63;
  const int wv = tid >> 6;
  const int o = lane & 15;
  const int g = lane >> 4;
  const int wm = wv & 1;          // row half (32 rows)
  const int wn = wv >> 1;         // 0..3
  const int base = blockIdx.x * 64;

  const float rs128 = 0.08838834764831845f;
  const float inv16 = 0.0625f;
  const float rs32  = 0.17677669529663687f;

  // ---- stage scalars [64][128] bf16 (slot16 ^= row&15) -----------------
#pragma unroll
  for (int R = 0; R < 2; ++R) {
    int fbi = R * 512 + tid;                 // 16B-unit index 0..1023
    int row = fbi >> 4, j = fbi & 15;
    u16x8 v = *(const u16x8*)(fB + (size_t)(base + row) * FDIM + j * 8);
    *(u16x8*)(smem + STG + row * 256 + ((j ^ (row & 15)) << 4)) = v;
  }
  __syncthreads();

  // frag readers
#define AFRAG(ROW, KS) \
  (*(const bf16x8*)(smem + STG + (ROW) * 256 + ((((KS) * 4 + g) ^ ((ROW) & 15)) << 4)))
#define HFRAG(ROW, KK) \
  (*(const bf16x8*)(smem + HB + (ROW) * 512 + ((((KK) * 4 + g) ^ ((ROW) & 15)) << 4)))

  // ================= A1: H[:,0:256] = silu(S @ W1[:,0:256]) ============
  f32x4 acc[2][4];
#pragma unroll
  for (int mt = 0; mt < 2; ++mt)
#pragma unroll
    for (int nt = 0; nt < 4; ++nt) acc[mt][nt] = (f32x4){0.f, 0.f, 0.f, 0.f};

#pragma unroll
  for (int ks = 0; ks < 4; ++ks) {
    bf16x8 a0 = AFRAG(wm * 32 + o, ks);
    bf16x8 a1 = AFRAG(wm * 32 + 16 + o, ks);
#pragma unroll
    for (int nt = 0; nt < 4; ++nt) {
      bf16x8 b = *(const bf16x8*)(W1T + (wn * 64 + nt * 16 + o) * 128 + ks * 32 + g * 8);
      acc[0][nt] = __builtin_amdgcn_mfma_f32_16x16x32_bf16(a0, b, acc[0][nt], 0, 0, 0);
      acc[1][nt] = __builtin_amdgcn_mfma_f32_16x16x32_bf16(a1, b, acc[1][nt], 0, 0, 0);
    }
  }
#pragma unroll
  for (int mt = 0; mt < 2; ++mt)
#pragma unroll
    for (int nt = 0; nt < 4; ++nt)
#pragma unroll
      for (int r = 0; r < 4; ++r) {
        int row = wm * 32 + mt * 16 + g * 4 + r;
        int col = wn * 64 + nt * 16 + o;
        float v = acc[mt][nt][r] * rs128;
        float h = v / (1.f + __expf(-v));
        *(unsigned short*)(smem + HB + row * 512 + ((col * 2) ^ ((row & 15) << 4))) = f2bf(h);
      }
  __syncthreads();

  // ======== B-inv (H1 @ invW2) + A2 compute (no LDS writes yet) ========
  f32x4 acc2[2] = {(f32x4){0.f, 0.f, 0.f, 0.f}, (f32x4){0.f, 0.f, 0.f, 0.f}};
#pragma unroll
  for (int kk = 0; kk < 8; ++kk) {
    bf16x8 h0 = HFRAG(wm * 32 + o, kk);
    bf16x8 h1 = HFRAG(wm * 32 + 16 + o, kk);
    bf16x8 b = *(const bf16x8*)(W2T + (wn * 16 + o) * 256 + kk * 32 + g * 8);
    acc2[0] = __builtin_amdgcn_mfma_f32_16x16x32_bf16(h0, b, acc2[0], 0, 0, 0);
    acc2[1] = __builtin_amdgcn_mfma_f32_16x16x32_bf16(h1, b, acc2[1], 0, 0, 0);
  }
#pragma unroll
  for (int mt = 0; mt < 2; ++mt)
#pragma unroll
    for (int nt = 0; nt < 4; ++nt) acc[mt][nt] = (f32x4){0.f, 0.f, 0.f, 0.f};
#pragma unroll
  for (int ks = 0; ks < 4; ++ks) {
    bf16x8 a0 = AFRAG(wm * 32 + o, ks);
    bf16x8 a1 = AFRAG(wm * 32 + 16 + o, ks);
#pragma unroll
    for (int nt = 0; nt < 4; ++nt) {
      bf16x8 b = *(const bf16x8*)(W1T + (256 + wn * 64 + nt * 16 + o) * 128 + ks * 32 + g * 8);
      acc[0][nt] = __builtin_amdgcn_mfma_f32_16x16x32_bf16(a0, b, acc[0][nt], 0, 0, 0);
      acc[1][nt] = __builtin_amdgcn_mfma_f32_16x16x32_bf16(a1, b, acc[1][nt], 0, 0, 0);
    }
  }
  // inv stores
#pragma unroll
  for (int mt = 0; mt < 2; ++mt)
#pragma unroll
    for (int r = 0; r < 4; ++r) {
      int node = base + wm * 32 + mt * 16 + g * 4 + r;
      if (node < NN) {
        float s = act[node] ? inv16 : 0.f;
        __builtin_nontemporal_store(acc2[mt][r] * s, out + (size_t)node * OUTC + wn * 16 + o);
      }
    }
  __syncthreads();             // all H1 reads done

  // A2 -> Hbuf (silu)
#pragma unroll
  for (int mt = 0; mt < 2; ++mt)
#pragma unroll
    for (int nt = 0; nt < 4; ++nt)
#pragma unroll
      for (int r = 0; r < 4; ++r) {
        int row = wm * 32 + mt * 16 + g * 4 + r;
        int col = wn * 64 + nt * 16 + o;
        float v = acc[mt][nt][r] * rs128;
        float h = v / (1.f + __expf(-v));
        *(unsigned short*)(smem + HB + row * 512 + ((col * 2) ^ ((row & 15) << 4))) = f2bf(h);
      }

  // phase-C x prefetch (96 bf16/node) + act
  const int nloc = tid >> 3;
  const int q = tid & 7;
  const int nodeC = base + nloc;
  u16x8 xr[12];
#pragma unroll
  for (int j = 0; j < 12; ++j)
    xr[j] = *(const u16x8*)(fB + (size_t)nodeC * FDIM + 128 + j * 8);
  const float sC = act[nodeC] ? rs32 : 0.f;
  __syncthreads();             // Hbuf(H2) ready

  // ======== B-wemb in 4 col-quarters + phase-C partials =================
  float eq[6] = {0.f, 0.f, 0.f, 0.f, 0.f, 0.f};
  f32x4 aq[2][2];

#define WEMBQ(QQ, BP) do { \
    _Pragma("unroll") \
    for (int mt_ = 0; mt_ < 2; ++mt_) \
      _Pragma("unroll") \
      for (int nt_ = 0; nt_ < 2; ++nt_) aq[mt_][nt_] = (f32x4){0.f, 0.f, 0.f, 0.f}; \
    _Pragma("unroll") \
    for (int kk_ = 0; kk_ < 8; ++kk_) { \
      bf16x8 h0_ = HFRAG(wm * 32 + o, kk_); \
      bf16x8 h1_ = HFRAG(wm * 32 + 16 + o, kk_); \
      _Pragma("unroll") \
      for (int nt_ = 0; nt_ < 2; ++nt_) { \
        bf16x8 b_ = *(const bf16x8*)(W2T + 16384 + ((QQ) * 128 + wn * 32 + nt_ * 16 + o) * 256 + kk_ * 32 + g * 8); \
        aq[0][nt_] = __builtin_amdgcn_mfma_f32_16x16x32_bf16(h0_, b_, aq[0][nt_], 0, 0, 0); \
        aq[1][nt_] = __builtin_amdgcn_mfma_f32_16x16x32_bf16(h1_, b_, aq[1][nt_], 0, 0, 0); \
      } \
    } \
    _Pragma("unroll") \
    for (int mt_ = 0; mt_ < 2; ++mt_) \
      _Pragma("unroll") \
      for (int nt_ = 0; nt_ < 2; ++nt_) \
        _Pragma("unroll") \
        for (int r_ = 0; r_ < 4; ++r_) { \
          int n_ = wm * 32 + mt_ * 16 + g * 4 + r_; \
          int lc_ = wn * 32 + nt_ * 16 + o; \
          *(unsigned short*)(smem + (BP) + n_ * 256 + ((lc_ * 2) ^ ((n_ & 7) << 5))) = \
              f2bf(aq[mt_][nt_][r_] * inv16); \
        } \
  } while (0)

#define CPART(QQ, BP) do { \
    _Pragma("unroll") \
    for (int il_ = 0; il_ < 8; ++il_) { \
      u16x2 w2_ = *(const u16x2*)(smem + (BP) + nloc * 256 + ((il_ * 32 + q * 4) ^ ((nloc & 7) << 5))); \
      float w0_ = bf2f(w2_[0]), w1_ = bf2f(w2_[1]); \
      _Pragma("unroll") \
      for (int m_ = 0; m_ < 3; ++m_) { \
        int xi_ = ((QQ) * 8 + il_) * 3 + m_; \
        float xv_ = bf2f((unsigned short)xr[xi_ >> 3][xi_ & 7]); \
        eq[m_] += xv_ * w0_; \
        eq[3 + m_] += xv_ * w1_; \
      } \
    } \
  } while (0)

  WEMBQ(0, STG);
  __syncthreads();
  WEMBQ(1, WMB);
  CPART(0, STG);
  __syncthreads();
  WEMBQ(2, STG);
  CPART(1, WMB);
  __syncthreads();
  WEMBQ(3, WMB);
  CPART(2, STG);
  __syncthreads();
  CPART(3, WMB);

  if (nodeC < NN) {
    float* op = out + (size_t)nodeC * OUTC + 64 + q * 6;
    __builtin_nontemporal_store((f32x2){eq[0] * sC, eq[1] * sC}, (f32x2*)(op + 0));
    __builtin_nontemporal_store((f32x2){eq[2] * sC, eq[3] * sC}, (f32x2*)(op + 2));
    __builtin_nontemporal_store((f32x2){eq[4] * sC, eq[5] * sC}, (f32x2*)(op + 4));
  }
#undef WEMBQ
#undef CPART
#undef AFRAG
#undef HFRAG
}

// ---- launch ------------------------------------------------------------
extern "C" void kernel_launch(void* const* d_in, const int* in_sizes, int n_in,
                              void* d_out, int out_size, void* d_ws, size_t ws_size,
                              hipStream_t stream) {
  const float* feats = (const float*)d_in[0];
  const int* ei = (const int*)d_in[1];
  const float* invW1 = (const float*)d_in[2];
  const float* invW2 = (const float*)d_in[3];
  const float* wembW1 = (const float*)d_in[4];
  const float* wembW2 = (const float*)d_in[5];
  float* out = (float*)d_out;

  char* ws = (char*)d_ws;
  unsigned short* W1T = (unsigned short*)ws;                      // 131072 B
  unsigned short* W2T = (unsigned short*)(ws + 131072);           // 294912 B
  unsigned char* act = (unsigned char*)(ws + 131072 + 294912);    // 100096 B
  unsigned short* fB = (unsigned short*)(ws + 131072 + 294912 + 100096);  // 44.8 MB

  k_zero<<<98, 256, 0, stream>>>((unsigned int*)act, 25024);
  k_scatter<<<6250, 256, 0, stream>>>(ei, act);
  k_wprep<<<832, 256, 0, stream>>>(invW1, invW2, wembW1, wembW2, W1T, W2T);
  k_fprep<<<2048, 256, 0, stream>>>(feats, fB);
  k_main<<<1563, 512, 0, stream>>>(fB, W1T, W2T, act, out);
}

// Round 9
// 184.712 us; speedup vs baseline: 1.9713x; 1.2551x over previous
//
#include <hip/hip_runtime.h>

#define NN 100000
#define EE 1600000
#define FDIM 224
#define OUTC 112

// LDS byte offsets
#define SPO 0        // staged scalars  [32 rows][16 slots][16B]  (8KB)
#define HO  8192     // H buffer [32 rows][512 cols bf16], XOR (row&15)<<4 (32KB)
#define WBA 40960    // weight chunk ping (8KB)
#define WBB 49152    // weight chunk pong (8KB)
#define WMA 57344    // Wm quarter ping (8KB)
#define WMB2 65536   // Wm quarter pong (8KB)
#define LDSZ 73728

typedef __attribute__((ext_vector_type(8))) short bf16x8;
typedef __attribute__((ext_vector_type(8))) unsigned short u16x8;
typedef __attribute__((ext_vector_type(4))) float f32x4;

__device__ __forceinline__ unsigned short f2bf(float f) {
  unsigned u = __builtin_bit_cast(unsigned, f);
  u = (u + 0x7FFFu + ((u >> 16) & 1u)) >> 16;   // RNE
  return (unsigned short)u;
}
__device__ __forceinline__ float bf2f(unsigned short h) {
  return __builtin_bit_cast(float, (unsigned)h << 16);
}
// one wave-instruction: stages 64 lanes x 16B = 1KB global->LDS (no VGPR round trip)
__device__ __forceinline__ void gl_lds16(const unsigned short* g, char* l) {
  __builtin_amdgcn_global_load_lds(
      (const __attribute__((address_space(1))) unsigned int*)g,
      (__attribute__((address_space(3))) unsigned int*)l, 16, 0, 0);
}

// ---- prep kernels ------------------------------------------------------
__global__ void k_zero(unsigned int* p, int n) {
  int i = blockIdx.x * 256 + threadIdx.x;
  if (i < n) p[i] = 0u;
}

__global__ void k_scatter(const int* __restrict__ ei, unsigned char* __restrict__ act) {
  int e = blockIdx.x * 256 + threadIdx.x;
  if (e < EE) {
    int n = ei[e];
    if (!act[n]) act[n] = 1;
  }
}

// Weight repack into 8KB chunks == exact LDS images.
// chunk element (r128, g, e) at u16 idx  r128*32 + ((g ^ (r128&3))*8) + e
// W1s: 16 chunks c = QQ*4+ks   : n=QQ*128+r128 (col of [invW1|wembW1]), k=ks*32+g*8+e
// W2w: 32 chunks c = QQ*8+kk   : n=QQ*128+r128 (wemb col),              k=kk*32+g*8+e
// W2i: [64][256] row-major (inv cols x k)
__global__ void k_wprep(const float* __restrict__ invW1, const float* __restrict__ invW2,
                        const float* __restrict__ wembW1, const float* __restrict__ wembW2,
                        unsigned short* __restrict__ W1s, unsigned short* __restrict__ W2w,
                        unsigned short* __restrict__ W2i) {
  int i = blockIdx.x * 256 + threadIdx.x;   // 0..212991
  if (i < 65536) {
    int c = i >> 12, j = i & 4095;
    int r128 = j >> 5, slot = (j >> 3) & 3, e = j & 7;
    int gg = slot ^ (r128 & 3);
    int n = (c >> 2) * 128 + r128;
    int k = (c & 3) * 32 + gg * 8 + e;
    float v = (n < 256) ? invW1[k * 256 + n] : wembW1[k * 256 + (n - 256)];
    W1s[i] = f2bf(v);
  } else if (i < 196608) {
    int t = i - 65536;
    int c = t >> 12, j = t & 4095;
    int r128 = j >> 5, slot = (j >> 3) & 3, e = j & 7;
    int gg = slot ^ (r128 & 3);
    int n = (c >> 3) * 128 + r128;
    int k = (c & 7) * 32 + gg * 8 + e;
    W2w[t] = f2bf(wembW2[k * 512 + n]);
  } else if (i < 212992) {
    int t = i - 196608;
    int n = t >> 8, k = t & 255;
    W2i[t] = f2bf(invW2[k * 64 + n]);
  }
}

// feats -> SPg (scalars, per-32-node 8KB LDS images, pre-swizzled) + XPg (x, bf16 row-major)
__global__ void k_fprep(const float* __restrict__ feats,
                        unsigned short* __restrict__ SPg, unsigned short* __restrict__ XPg) {
  const int TOT = NN * 16 + NN * 12;
  for (int u = blockIdx.x * 256 + threadIdx.x; u < TOT; u += gridDim.x * 256) {
    u16x8 v;
    if (u < NN * 16) {
      int node = u >> 4, k4 = u & 15;
      const float* p = feats + (size_t)node * FDIM + k4 * 8;
      f32x4 a = *(const f32x4*)p, b = *(const f32x4*)(p + 4);
      v[0] = f2bf(a[0]); v[1] = f2bf(a[1]); v[2] = f2bf(a[2]); v[3] = f2bf(a[3]);
      v[4] = f2bf(b[0]); v[5] = f2bf(b[1]); v[6] = f2bf(b[2]); v[7] = f2bf(b[3]);
      int row = node & 31;
      *(u16x8*)(SPg + (size_t)(node >> 5) * 4096 + row * 128 + ((k4 ^ (row & 15)) * 8)) = v;
    } else {
      int t = u - NN * 16;
      int node = t / 12, j = t - node * 12;
      const float* p = feats + (size_t)node * FDIM + 128 + j * 8;
      f32x4 a = *(const f32x4*)p, b = *(const f32x4*)(p + 4);
      v[0] = f2bf(a[0]); v[1] = f2bf(a[1]); v[2] = f2bf(a[2]); v[3] = f2bf(a[3]);
      v[4] = f2bf(b[0]); v[5] = f2bf(b[1]); v[6] = f2bf(b[2]); v[7] = f2bf(b[3]);
      *(u16x8*)(XPg + (size_t)node * 96 + j * 8) = v;
    }
  }
}

// ---- fused main kernel: staged 2-phase pipeline -------------------------
// 32 nodes/block, 512 thr (8 waves), LDS 72KB -> 2 blocks/CU. Grid 3125 exact.
__global__ __launch_bounds__(512, 4) void k_main(
    const unsigned short* __restrict__ SPg,
    const unsigned short* __restrict__ XPg,
    const unsigned short* __restrict__ W1s,
    const unsigned short* __restrict__ W2w,
    const unsigned short* __restrict__ W2i,
    const unsigned char* __restrict__ act,
    float* __restrict__ out) {
  __shared__ char smem[LDSZ];
  const int tid = threadIdx.x;
  const int lane = tid & 63;
  const int wv = tid >> 6;
  const int o = lane & 15;
  const int g = lane >> 4;
  const int base = blockIdx.x * 32;
  const int mtw = wv & 1, ct = wv >> 1;      // inv tile roles
  const int nloc = tid >> 4, q = tid & 15;   // phase-C roles

  const float rs128 = 0.08838834764831845f;
  const float inv16 = 0.0625f;
  const float rs32  = 0.17677669529663687f;

  // --- prologue: stage scalars + W1 chunk0; issue x/act loads ----------
  gl_lds16(SPg + (size_t)blockIdx.x * 4096 + wv * 512 + lane * 8, smem + SPO + wv * 1024);
  gl_lds16(W1s + wv * 512 + lane * 8, smem + WBA + wv * 1024);
  u16x8 xr[12];
#pragma unroll
  for (int j = 0; j < 12; ++j)
    xr[j] = *(const u16x8*)(XPg + (size_t)(base + nloc) * 96 + j * 8);
  const float sC = act[base + nloc] ? rs32 : 0.f;
  __syncthreads();

  // reusable address pieces
  const int aoff0 = SPO + o * 256;           // row o
  const int aoff1 = SPO + (16 + o) * 256;    // row 16+o (same slot xor: (16+o)&15==o)
  const int woff = (wv * 16 + o) * 64;       // b-frag row in chunk
  const int wslot = (g ^ (o & 3)) << 4;
  const int hro0 = HO + o * 1024, hro1 = HO + (16 + o) * 1024;
  const int hx = (o & 15) << 4;

  f32x4 acc0 = (f32x4){0.f, 0.f, 0.f, 0.f};
  f32x4 acc1 = (f32x4){0.f, 0.f, 0.f, 0.f};
  f32x4 acc2 = (f32x4){0.f, 0.f, 0.f, 0.f};
  float eq0 = 0.f, eq1 = 0.f, eq2 = 0.f;

  // ================= A phase: 16 steps (QQ = s>>2, ks = s&3) ===========
#pragma unroll
  for (int s = 0; s < 16; ++s) {
    const int ks = s & 3, QQ = s >> 2;
    // stage next chunk (issued BEFORE compute; drained at the step barrier)
    if (s < 15)
      gl_lds16(W1s + (s + 1) * 4096 + wv * 512 + lane * 8,
               smem + (((s + 1) & 1) ? WBB : WBA) + wv * 1024);
    else
      gl_lds16(W2w + wv * 512 + lane * 8, smem + WBA + wv * 1024);
    // compute current chunk
    {
      const int slot = ((ks * 4 + g) ^ (o & 15)) << 4;
      bf16x8 a0 = *(const bf16x8*)(smem + aoff0 + slot);
      bf16x8 a1 = *(const bf16x8*)(smem + aoff1 + slot);
      bf16x8 b = *(const bf16x8*)(smem + ((s & 1) ? WBB : WBA) + woff + wslot);
      acc0 = __builtin_amdgcn_mfma_f32_16x16x32_bf16(a0, b, acc0, 0, 0, 0);
      acc1 = __builtin_amdgcn_mfma_f32_16x16x32_bf16(a1, b, acc1, 0, 0, 0);
    }
    // interleaved B-inv (k-step kk = s-8), H cols 0..255 ready after s=7
    if (s >= 8) {
      const int kk = s - 8;
      bf16x8 hi = *(const bf16x8*)(smem + HO + (mtw * 16 + o) * 1024 + ((kk * 64 + g * 16) ^ (o << 4)));
      bf16x8 b2 = *(const bf16x8*)(W2i + (ct * 16 + o) * 256 + kk * 32 + g * 8);
      acc2 = __builtin_amdgcn_mfma_f32_16x16x32_bf16(hi, b2, acc2, 0, 0, 0);
    }
    // per-QQ epilogue: silu -> H
    if (ks == 3) {
#pragma unroll
      for (int mt = 0; mt < 2; ++mt) {
        f32x4 a = mt ? acc1 : acc0;
#pragma unroll
        for (int r = 0; r < 4; ++r) {
          int row = mt * 16 + g * 4 + r;
          int col = QQ * 128 + wv * 16 + o;
          float v = a[r] * rs128;
          float h = v / (1.f + __expf(-v));
          *(unsigned short*)(smem + HO + row * 1024 + ((col * 2) ^ ((row & 15) << 4))) = f2bf(h);
        }
      }
      acc0 = (f32x4){0.f, 0.f, 0.f, 0.f};
      acc1 = (f32x4){0.f, 0.f, 0.f, 0.f};
    }
    __syncthreads();
  }

  // inv output (cols 0..63), masked
#pragma unroll
  for (int r = 0; r < 4; ++r) {
    int node = base + mtw * 16 + g * 4 + r;
    float ss = act[node] ? inv16 : 0.f;
    __builtin_nontemporal_store(acc2[r] * ss, out + (size_t)node * OUTC + ct * 16 + o);
  }

  // ================= B phase: 32 steps (QQ = t>>3, kk = t&7) ===========
#pragma unroll
  for (int t = 0; t < 32; ++t) {
    const int kk = t & 7, QQ = t >> 3;
    if (t < 31)
      gl_lds16(W2w + (t + 1) * 4096 + wv * 512 + lane * 8,
               smem + (((t + 1) & 1) ? WBB : WBA) + wv * 1024);
    {
      const int hb = 512 + kk * 64 + g * 16;
      bf16x8 h0 = *(const bf16x8*)(smem + hro0 + (hb ^ hx));
      bf16x8 h1 = *(const bf16x8*)(smem + hro1 + (hb ^ hx));
      bf16x8 b = *(const bf16x8*)(smem + ((t & 1) ? WBB : WBA) + woff + wslot);
      acc0 = __builtin_amdgcn_mfma_f32_16x16x32_bf16(h0, b, acc0, 0, 0, 0);
      acc1 = __builtin_amdgcn_mfma_f32_16x16x32_bf16(h1, b, acc1, 0, 0, 0);
    }
    // phase-C slice for the previous quarter (1 il per step)
    if (t >= 8) {
      const int Qp = QQ - 1, il = kk;
      const int wmoff = (Qp & 1) ? WMB2 : WMA;
      unsigned short w = *(const unsigned short*)(
          smem + wmoff + nloc * 256 + (((il * 16 + q) * 2) ^ ((nloc & 7) << 5)));
      float wf = bf2f(w);
      eq0 += bf2f((unsigned short)xr[(Qp * 24 + il * 3 + 0) >> 3][(Qp * 24 + il * 3 + 0) & 7]) * wf;
      eq1 += bf2f((unsigned short)xr[(Qp * 24 + il * 3 + 1) >> 3][(Qp * 24 + il * 3 + 1) & 7]) * wf;
      eq2 += bf2f((unsigned short)xr[(Qp * 24 + il * 3 + 2) >> 3][(Qp * 24 + il * 3 + 2) & 7]) * wf;
    }
    // per-QQ epilogue: acc -> Wm ping-pong
    if (kk == 7) {
      const int wmoff = (QQ & 1) ? WMB2 : WMA;
#pragma unroll
      for (int mt = 0; mt < 2; ++mt) {
        f32x4 a = mt ? acc1 : acc0;
#pragma unroll
        for (int r = 0; r < 4; ++r) {
          int n = mt * 16 + g * 4 + r;
          int lc = wv * 16 + o;
          *(unsigned short*)(smem + wmoff + n * 256 + ((lc * 2) ^ ((n & 7) << 5))) =
              f2bf(a[r] * inv16);
        }
      }
      acc0 = (f32x4){0.f, 0.f, 0.f, 0.f};
      acc1 = (f32x4){0.f, 0.f, 0.f, 0.f};
    }
    __syncthreads();
  }

  // final quarter's phase-C slices (Wm in WMB2, barrier already passed)
#pragma unroll
  for (int il = 0; il < 8; ++il) {
    unsigned short w = *(const unsigned short*)(
        smem + WMB2 + nloc * 256 + (((il * 16 + q) * 2) ^ ((nloc & 7) << 5)));
    float wf = bf2f(w);
    eq0 += bf2f((unsigned short)xr[(72 + il * 3 + 0) >> 3][(72 + il * 3 + 0) & 7]) * wf;
    eq1 += bf2f((unsigned short)xr[(72 + il * 3 + 1) >> 3][(72 + il * 3 + 1) & 7]) * wf;
    eq2 += bf2f((unsigned short)xr[(72 + il * 3 + 2) >> 3][(72 + il * 3 + 2) & 7]) * wf;
  }

  float* op = out + (size_t)(base + nloc) * OUTC + 64 + q * 3;
  __builtin_nontemporal_store(eq0 * sC, op + 0);
  __builtin_nontemporal_store(eq1 * sC, op + 1);
  __builtin_nontemporal_store(eq2 * sC, op + 2);
}

// ---- launch ------------------------------------------------------------
extern "C" void kernel_launch(void* const* d_in, const int* in_sizes, int n_in,
                              void* d_out, int out_size, void* d_ws, size_t ws_size,
                              hipStream_t stream) {
  const float* feats = (const float*)d_in[0];
  const int* ei = (const int*)d_in[1];
  const float* invW1 = (const float*)d_in[2];
  const float* invW2 = (const float*)d_in[3];
  const float* wembW1 = (const float*)d_in[4];
  const float* wembW2 = (const float*)d_in[5];
  float* out = (float*)d_out;

  char* ws = (char*)d_ws;
  unsigned short* W1s = (unsigned short*)(ws);                    // 131072 B
  unsigned short* W2w = (unsigned short*)(ws + 131072);           // 262144 B
  unsigned short* W2i = (unsigned short*)(ws + 393216);           // 32768 B
  unsigned char* act  = (unsigned char*)(ws + 425984);            // 100096 B
  unsigned short* SPg = (unsigned short*)(ws + 526080);           // 25600000 B
  unsigned short* XPg = (unsigned short*)(ws + 26126080);         // 19200000 B

  k_zero<<<98, 256, 0, stream>>>((unsigned int*)act, 25024);
  k_scatter<<<6250, 256, 0, stream>>>(ei, act);
  k_wprep<<<832, 256, 0, stream>>>(invW1, invW2, wembW1, wembW2, W1s, W2w, W2i);
  k_fprep<<<2048, 256, 0, stream>>>(feats, SPg, XPg);
  k_main<<<3125, 512, 0, stream>>>(SPg, XPg, W1s, W2w, W2i, act, out);
}